// Round 9
// baseline (693.659 us; speedup 1.0000x reference)
//
#include <hip/hip_runtime.h>

#define T_LEN 2048
#define HID   25
#define LOG2E 1.4426950408889634f

// may_alias vector for the LDS h-row readback (written as scalar float):
// without it, TBAA licenses hoisting the read above the publish (R3/R7 bug).
typedef float vf4 __attribute__((vector_size(16), may_alias));

__device__ __forceinline__ float fast_rcp(float x) { return __builtin_amdgcn_rcpf(x); }
__device__ __forceinline__ float fast_exp2(float x) { return __builtin_amdgcn_exp2f(x); }

// R9 = R4 layout + R8 fixes.
// One chain per 64-lane wave: lower lane u owns rows i_u,g_u; upper lane 32+u
// owns f_u,o_u (50 fp32 weights/lane). 2048 chains -> 2048 waves = 2 waves/SIMD
// so each wave's LDS round-trip (~130 cyc) and trans chain (~80 cyc) hide under
// the sibling wave's issue (m114 co-scheduling); R8's 1-wave/SIMD layout had
// that latency fully exposed (29% of its 727 cyc/step).
// amdgpu_waves_per_eu(2,2): caps at 2 waves/EU -> 256-VGPR budget, enough for
// the ~90 live floats (R2-R6 showed the default allocator demotes weights to
// AGPRs, ~2x dynamic instructions; R8 proved the cap fixes it).
// sigmoid/tanh in exp2 domain (weights pre-scaled by -log2e / +2log2e);
// per-gate fma order identical to R5/R8 (two accumulators, k=0..11 / 12..24,
// both passed at exactly 1.953e-3).

__global__ __attribute__((amdgpu_flat_work_group_size(256, 256),
                          amdgpu_waves_per_eu(2, 2)))
void lstm_fused(
    const float* __restrict__ x,        // [B, T, 1]
    const float* __restrict__ w_ih,     // [100, 1]
    const float* __restrict__ w_hh,     // [100, 25]
    const float* __restrict__ b_ih,     // [100]
    const float* __restrict__ b_hh,     // [100]
    const float* __restrict__ w_dense,  // [1, 25]
    const float* __restrict__ b_dense,  // [1]
    float* __restrict__ out)            // [B, T, 1]
{
    const int tid  = threadIdx.x;
    const int L    = tid & 63;           // lane in wave
    const int u    = L & 31;             // hidden unit / t'-slot for this lane
    const bool up  = L >= 32;            // upper half: f/o rows, owns c and h
    const int cl   = tid >> 6;           // wave (= chain) index in block, 0..3
    const int b    = blockIdx.x * 4 + cl;
    const bool act = u < HID;

    // Two rows per wave: [2cl+0] = scratch (lower-half junk publishes),
    // [2cl+1] = real h (upper half's writes).
    __shared__ __align__(16) float hbuf[8][32];
    // h history for batched y: 32 steps x 33 floats (stride 33 keeps the
    // lane=u strided reads in the y phase conflict-free).
    __shared__ float hist[4][32][33];

    const int rowA = up ? (HID + u)     : u;              // f-row : i-row
    const int rowB = up ? (3 * HID + u) : (2 * HID + u);  // o-row : g-row
    const float sclA = -LOG2E;                            // sigmoid gates
    const float sclB = up ? -LOG2E : 2.f * LOG2E;         // o: sigmoid, g: tanh

    // ---- 50 recurrent fp32 weights per lane, pre-scaled into exp2 domain ----
    float wAv[HID], wBv[HID];
#pragma unroll
    for (int k = 0; k < HID; ++k) {
        wAv[k] = act ? sclA * w_hh[rowA * HID + k] : 0.f;
        wBv[k] = act ? sclB * w_hh[rowB * HID + k] : 0.f;
    }
    const float bA  = act ? sclA * (b_ih[rowA] + b_hh[rowA]) : 0.f;
    const float bB  = act ? sclB * (b_ih[rowB] + b_hh[rowB]) : 0.f;
    const float wxA = act ? sclA * w_ih[rowA] : 0.f;
    const float wxB = act ? sclB * w_ih[rowB] : 0.f;
    const float bd  = b_dense[0];
    // tB = fmaf(-tmul, sB, 1): tanh(g) on lower half, exactly 1.0 on upper
    const float tmul = up ? 0.f : 2.f;

    // dense weights for the batched y: lower half sums u'=0..12, upper 13..24
    const int u0 = up ? 13 : 0;
    float wdv[13];
#pragma unroll
    for (int i = 0; i < 13; ++i) wdv[i] = (u0 + i < HID) ? w_dense[u0 + i] : 0.f;

    // h0 = 0 (both rows; pad slots 25..31 stay 0 for the b128 reads)
    if (L < 32) { hbuf[2 * cl][L] = 0.f; hbuf[2 * cl + 1][L] = 0.f; }

    float* hwr = &hbuf[2 * cl + (up ? 1 : 0)][u];
    const vf4* r4 = (const vf4*)&hbuf[2 * cl + 1][0];
    const float* hbF = &hbuf[2 * cl + 1][0];

    const float4* __restrict__ xp = (const float4*)(x + (size_t)b * T_LEN);
    float* __restrict__ orow = out + (size_t)b * T_LEN;

    // h state as loaded quads, used in place (no unpack movs)
    vf4 hq[6];
#pragma unroll
    for (int m = 0; m < 6; ++m) hq[m] = vf4{0.f, 0.f, 0.f, 0.f};
    float h24 = 0.f;

    float c = 0.f;        // real on upper half, bounded junk on lower
    float4 xcur = xp[0];

    for (int it = 0; it < T_LEN / 4; ++it) {
        const int nx = (it + 1 < T_LEN / 4) ? it + 1 : it;
        float4 xnext = xp[nx];  // issued ~4 steps ahead of use
        float xs[4] = {xcur.x, xcur.y, xcur.z, xcur.w};

#pragma unroll
        for (int s = 0; s < 4; ++s) {
            const float xv = xs[s];
            const int t = 4 * it + s;

            // gate pre-activations, two accumulators per gate (k=0..11 /
            // 12..24) -- fma order identical to R5/R8 (1.953e-3)
            float aA0 = fmaf(xv, wxA, bA), aA1 = 0.f;
            float aB0 = fmaf(xv, wxB, bB), aB1 = 0.f;
#pragma unroll
            for (int k = 0; k < 12; ++k) {
                const float h = hq[k >> 2][k & 3];
                aA0 = fmaf(h, wAv[k], aA0);
                aB0 = fmaf(h, wBv[k], aB0);
            }
#pragma unroll
            for (int k = 12; k < 24; ++k) {
                const float h = hq[k >> 2][k & 3];
                aA1 = fmaf(h, wAv[k], aA1);
                aB1 = fmaf(h, wBv[k], aB1);
            }
            aA1 = fmaf(h24, wAv[24], aA1);
            aB1 = fmaf(h24, wBv[24], aB1);
            const float aA = aA0 + aA1;     // lower: i-preact, upper: f-preact
            const float aB = aB0 + aB1;     // lower: g-preact, upper: o-preact

            const float sA = fast_rcp(1.f + fast_exp2(aA));  // sig(i) / sig(f)
            const float sB = fast_rcp(1.f + fast_exp2(aB));  // g-aux  / sig(o)
            const float tB = fmaf(-tmul, sB, 1.f);           // tanh(g) / 1.0
            const float vv = sA * tB;                        // i*tanh(g) / sig(f)
            const float ov = __shfl_xor(vv, 32, 64);         // swap halves

            c = fmaf(vv, c, ov);             // upper: f*c + i*g   (lower: junk)
            const float tC = fmaf(-2.f, fast_rcp(1.f + fast_exp2(2.f * LOG2E * c)), 1.f);
            const float hn = sB * tC;        // upper: o*tanh(c)   (lower: junk)

            // ---- ordered publish -> readback (fences are compile-time only;
            // same-wave DS ops execute in order on HW) ----
            *hwr = hn;                       // upper -> real row, lower -> scratch
            if (up && act) hist[cl][t & 31][u] = hn;
            __asm__ __volatile__("" ::: "memory");
            hq[0] = r4[0]; hq[1] = r4[1]; hq[2] = r4[2];
            hq[3] = r4[3]; hq[4] = r4[4]; hq[5] = r4[5];
            h24 = hbF[24];
            __asm__ __volatile__("" ::: "memory");

            // batched y: every 32 steps lane L computes its half-sum of
            // y[t0 + u]; shfl_xor(32) combines halves; lower half stores.
            if ((t & 31) == 31) {
                const float* hrow = &hist[cl][u][0];   // row for t' = t0 + u
                float ys = 0.f;
#pragma unroll
                for (int i = 0; i < 13; ++i)
                    ys = fmaf(hrow[u0 + i], wdv[i], ys);   // [25] pad reads 0*0
                ys += __shfl_xor(ys, 32, 64);
                if (!up) orow[(t & ~31) + u] = ys + bd;    // 128 B coalesced
            }
        }
        xcur = xnext;
    }
}

extern "C" void kernel_launch(void* const* d_in, const int* in_sizes, int n_in,
                              void* d_out, int out_size, void* d_ws, size_t ws_size,
                              hipStream_t stream) {
    const float* x       = (const float*)d_in[0];
    const float* w_ih    = (const float*)d_in[1];
    const float* w_hh    = (const float*)d_in[2];
    const float* b_ih    = (const float*)d_in[3];
    const float* b_hh    = (const float*)d_in[4];
    const float* w_dense = (const float*)d_in[5];
    const float* b_dense = (const float*)d_in[6];
    float* out = (float*)d_out;

    // 2048 chains, one per 64-lane wave: 512 blocks x 256 threads
    // -> 2 blocks/CU, 8 waves/CU = 2 waves/SIMD (sibling-wave latency hiding).
    lstm_fused<<<dim3(512), dim3(256), 0, stream>>>(x, w_ih, w_hh, b_ih, b_hh,
                                                    w_dense, b_dense, out);
}